// Round 2
// baseline (214.569 us; speedup 1.0000x reference)
//
#include <hip/hip_runtime.h>

#define L_LEN   16384
#define P_DIM   512
#define CHUNK   32
#define NCHUNK  512        // L_LEN / CHUNK

#define KDIM    1024       // 2*P, interleaved: k=2c -> re(ch c), k=2c+1 -> im(ch c)
#define NDIM    512

typedef __bf16 bf16_t;
typedef __bf16 bf16x8 __attribute__((ext_vector_type(8)));
typedef float  floatx4 __attribute__((ext_vector_type(4)));

// Per-channel discretization constants: a = exp(lambda*step), B = (a-1)/lambda
__device__ __forceinline__ void channel_consts(const float* __restrict__ Lam,
                                               const float* __restrict__ lstep,
                                               int p, float& ar, float& ai,
                                               float& br, float& bi) {
    float lr = -expf(Lam[2 * p + 0]);     // Re(lambda) < 0
    float li = Lam[2 * p + 1];            // Im(lambda)
    float s  = expf(lstep[p]);
    float er = expf(lr * s);
    ar = er * cosf(li * s);
    ai = er * sinf(li * s);
    float dr = ar - 1.0f, di = ai;
    float inv = 1.0f / (lr * lr + li * li);
    br = (dr * lr + di * li) * inv;
    bi = (di * lr - dr * li) * inv;
}

// Phase 1: per (chunk, channel) local scan (zero init), write end state.
// 512 blocks x 512 threads -> full GPU.
__global__ void __launch_bounds__(P_DIM) k_scan_ends(const float* __restrict__ u,
        const float* __restrict__ Lam, const float* __restrict__ lstep,
        float2* __restrict__ endv) {
    int p = threadIdx.x;
    int c = blockIdx.x;
    float ar, ai, br, bi;
    channel_consts(Lam, lstep, p, ar, ai, br, bi);
    float xr = 0.f, xi = 0.f;
    const float* up = u + (size_t)c * CHUNK * P_DIM + p;
    #pragma unroll 8
    for (int k = 0; k < CHUNK; ++k) {
        float uv = up[(size_t)k * P_DIM];
        float nr = ar * xr - ai * xi + br * uv;
        float ni = ar * xi + ai * xr + bi * uv;
        xr = nr; xi = ni;
    }
    endv[c * P_DIM + p] = make_float2(xr, xi);
}

// Phase 2: sequential scan over chunk carries (1 block, 512 threads).
__global__ void __launch_bounds__(P_DIM) k_carry(const float* __restrict__ Lam,
        const float* __restrict__ lstep, const float2* __restrict__ endv,
        float2* __restrict__ carry) {
    int p = threadIdx.x;
    float lr = -expf(Lam[2 * p + 0]);
    float li = Lam[2 * p + 1];
    float s  = expf(lstep[p]);
    float t  = s * (float)CHUNK;
    float er = expf(lr * t);
    float Ar = er * cosf(li * t);
    float Ai = er * sinf(li * t);
    float xr = 0.f, xi = 0.f;
    #pragma unroll 8
    for (int c = 0; c < NCHUNK; ++c) {
        carry[c * P_DIM + p] = make_float2(xr, xi);
        float2 e = endv[c * P_DIM + p];
        float nr = Ar * xr - Ai * xi + e.x;
        float ni = Ar * xi + Ai * xr + e.y;
        xr = nr; xi = ni;
    }
}

// Pack B operand, K interleaved: Bt[j][2c]=V_re[j][c], Bt[j][2c+1]=-V_im[j][c].
// One packed dword store per thread; dword index == j*512+c == idx.
__global__ void __launch_bounds__(256) k_bt(const float* __restrict__ Vre,
        const float* __restrict__ Vim, bf16_t* __restrict__ Bt) {
    int idx = blockIdx.x * 256 + threadIdx.x;   // 0 .. 512*512-1
    int j = idx >> 9;
    int c = idx & 511;
    union { unsigned int w; bf16_t h[2]; } pk;
    pk.h[0] = (bf16_t)Vre[j * P_DIM + c];
    pk.h[1] = (bf16_t)(-Vim[j * P_DIM + c]);
    ((unsigned int*)Bt)[idx] = pk.w;
}

// Fused scan + GEMM. Block c: re-run local scan for chunk c (32 steps, carry
// init), write bf16 A-tile [32][1024] into LDS (XOR-swizzled 16B chunks:
// phys_chunk = (k>>3) ^ (t&7) -> 2-way bank aliasing only). Then
// out[32 x 512] = A(LDS) x Bt(global, L2-hot)^T with spike epilogue.
// 512 threads = 8 waves; wave w covers n in [w*64, w*64+64).
__global__ void __launch_bounds__(512, 4) k_fused(const float* __restrict__ u,
        const float* __restrict__ Lam, const float* __restrict__ lstep,
        const float2* __restrict__ carry, const bf16_t* __restrict__ Bt,
        float* __restrict__ out) {
    __shared__ __align__(16) bf16_t As[CHUNK * KDIM];   // 64 KB

    const int tid = threadIdx.x;
    const int c   = blockIdx.x;

    // ---- scan phase: thread p owns channel p ----
    {
        const int p = tid;
        float ar, ai, br, bi;
        channel_consts(Lam, lstep, p, ar, ai, br, bi);
        float2 x0 = carry[c * P_DIM + p];
        float xr = x0.x, xi = x0.y;
        const float* up = u + (size_t)c * CHUNK * P_DIM + p;
        unsigned int* As32 = (unsigned int*)As;
        const int scol = p >> 2;      // 16B-chunk col for k=2p
        const int dwo  = p & 3;       // dword within chunk
        #pragma unroll 8
        for (int t = 0; t < CHUNK; ++t) {
            float uv = up[(size_t)t * P_DIM];
            float nr = ar * xr - ai * xi + br * uv;
            float ni = ar * xi + ai * xr + bi * uv;
            xr = nr; xi = ni;
            union { unsigned int w; bf16_t h[2]; } pk;
            pk.h[0] = (bf16_t)xr;
            pk.h[1] = (bf16_t)xi;
            int sc = scol ^ (t & 7);
            As32[t * (KDIM / 2) + sc * 4 + dwo] = pk.w;
        }
    }
    __syncthreads();

    // ---- GEMM phase ----
    const int lane = tid & 63;
    const int w    = tid >> 6;
    const int fr_m = lane & 15;
    const int fr_g = lane >> 4;
    const int nb   = w * 64;

    floatx4 acc[2][4];
    #pragma unroll
    for (int i = 0; i < 2; ++i)
        #pragma unroll
        for (int j = 0; j < 4; ++j) {
            floatx4 z = {0.f, 0.f, 0.f, 0.f};
            acc[i][j] = z;
        }

    #pragma unroll 2
    for (int kk = 0; kk < KDIM; kk += 32) {
        const int k0 = kk + fr_g * 8;
        bf16x8 af[2], bfr[4];
        #pragma unroll
        for (int j = 0; j < 4; ++j) {
            int n = nb + j * 16 + fr_m;
            bfr[j] = *(const bf16x8*)(Bt + (size_t)n * KDIM + k0);
        }
        #pragma unroll
        for (int i = 0; i < 2; ++i) {
            int m  = i * 16 + fr_m;
            int sc = (k0 >> 3) ^ (m & 7);
            af[i] = *(const bf16x8*)(As + m * KDIM + sc * 8);
        }
        #pragma unroll
        for (int i = 0; i < 2; ++i)
            #pragma unroll
            for (int j = 0; j < 4; ++j)
                acc[i][j] = __builtin_amdgcn_mfma_f32_16x16x32_bf16(
                    af[i], bfr[j], acc[i][j], 0, 0, 0);
    }

    // ---- epilogue: C/D layout col=lane&15, row=(lane>>4)*4+reg ----
    float* op = out + (size_t)c * CHUNK * NDIM;
    #pragma unroll
    for (int i = 0; i < 2; ++i)
        #pragma unroll
        for (int j = 0; j < 4; ++j)
            #pragma unroll
            for (int r = 0; r < 4; ++r) {
                int rr = i * 16 + fr_g * 4 + r;
                int cl = nb + j * 16 + fr_m;
                op[(size_t)rr * NDIM + cl] = (acc[i][j][r] > 1.0f) ? 1.0f : 0.0f;
            }
}

extern "C" void kernel_launch(void* const* d_in, const int* in_sizes, int n_in,
                              void* d_out, int out_size, void* d_ws, size_t ws_size,
                              hipStream_t stream) {
    (void)in_sizes; (void)n_in; (void)out_size; (void)ws_size;
    const float* u     = (const float*)d_in[0];
    const float* Lam   = (const float*)d_in[1];
    const float* lstep = (const float*)d_in[2];
    const float* Vre   = (const float*)d_in[3];
    const float* Vim   = (const float*)d_in[4];
    float* out = (float*)d_out;

    char* ws = (char*)d_ws;
    const size_t endv_bytes  = (size_t)NCHUNK * P_DIM * sizeof(float2);   // 2 MB
    const size_t carry_bytes = endv_bytes;                                // 2 MB
    float2* endv  = (float2*)(ws);
    float2* carry = (float2*)(ws + endv_bytes);
    bf16_t* Bt    = (bf16_t*)(ws + endv_bytes + carry_bytes);             // 1 MB

    hipLaunchKernelGGL(k_scan_ends, dim3(NCHUNK), dim3(P_DIM), 0, stream,
                       u, Lam, lstep, endv);
    hipLaunchKernelGGL(k_bt, dim3(NDIM * P_DIM / 256), dim3(256), 0, stream,
                       Vre, Vim, Bt);
    hipLaunchKernelGGL(k_carry, dim3(1), dim3(P_DIM), 0, stream,
                       Lam, lstep, endv, carry);
    hipLaunchKernelGGL(k_fused, dim3(NCHUNK), dim3(512), 0, stream,
                       u, Lam, lstep, carry, Bt, out);
}

// Round 3
// 155.555 us; speedup vs baseline: 1.3794x; 1.3794x over previous
//
#include <hip/hip_runtime.h>

#define L_LEN   16384
#define P_DIM   512
#define CHUNK   64
#define NCHUNK  256        // L_LEN / CHUNK

#define KDIM    1024       // 2*P, interleaved: k=2c -> re(ch c), k=2c+1 -> im(ch c)
#define NDIM    512
#define BM      128
#define BN      128
#define BK      64

typedef __bf16 bf16_t;
typedef __bf16 bf16x8 __attribute__((ext_vector_type(8)));
typedef float  floatx4 __attribute__((ext_vector_type(4)));

// Per-channel discretization constants: a = exp(lambda*step), B = (a-1)/lambda
__device__ __forceinline__ void channel_consts(const float* __restrict__ Lam,
                                               const float* __restrict__ lstep,
                                               int p, float& ar, float& ai,
                                               float& br, float& bi) {
    float lr = -expf(Lam[2 * p + 0]);     // Re(lambda) < 0
    float li = Lam[2 * p + 1];            // Im(lambda)
    float s  = expf(lstep[p]);
    float er = expf(lr * s);
    ar = er * cosf(li * s);
    ai = er * sinf(li * s);
    float dr = ar - 1.0f, di = ai;
    float inv = 1.0f / (lr * lr + li * li);
    br = (dr * lr + di * li) * inv;
    bi = (di * lr - dr * li) * inv;
}

// Phase 1: per (chunk, channel) local scan (zero init), write end state.
// 256 blocks x 512 threads -> full GPU.
__global__ void __launch_bounds__(P_DIM) k_scan_ends(const float* __restrict__ u,
        const float* __restrict__ Lam, const float* __restrict__ lstep,
        float2* __restrict__ endv) {
    int p = threadIdx.x;
    int c = blockIdx.x;
    float ar, ai, br, bi;
    channel_consts(Lam, lstep, p, ar, ai, br, bi);
    float xr = 0.f, xi = 0.f;
    const float* up = u + (size_t)c * CHUNK * P_DIM + p;
    #pragma unroll 8
    for (int k = 0; k < CHUNK; ++k) {
        float uv = up[(size_t)k * P_DIM];
        float nr = ar * xr - ai * xi + br * uv;
        float ni = ar * xi + ai * xr + bi * uv;
        xr = nr; xi = ni;
    }
    endv[c * P_DIM + p] = make_float2(xr, xi);
}

// Phase 2: sequential scan over chunk carries (1 block, 512 threads, 256 iters).
__global__ void __launch_bounds__(P_DIM) k_carry(const float* __restrict__ Lam,
        const float* __restrict__ lstep, const float2* __restrict__ endv,
        float2* __restrict__ carry) {
    int p = threadIdx.x;
    float lr = -expf(Lam[2 * p + 0]);
    float li = Lam[2 * p + 1];
    float s  = expf(lstep[p]);
    float t  = s * (float)CHUNK;
    float er = expf(lr * t);
    float Ar = er * cosf(li * t);
    float Ai = er * sinf(li * t);
    float xr = 0.f, xi = 0.f;
    #pragma unroll 8
    for (int c = 0; c < NCHUNK; ++c) {
        carry[c * P_DIM + p] = make_float2(xr, xi);
        float2 e = endv[c * P_DIM + p];
        float nr = Ar * xr - Ai * xi + e.x;
        float ni = Ar * xi + Ai * xr + e.y;
        xr = nr; xi = ni;
    }
}

// Pack B operand, K interleaved: Bt[j][2c]=V_re[j][c], Bt[j][2c+1]=-V_im[j][c].
__global__ void __launch_bounds__(256) k_bt(const float* __restrict__ Vre,
        const float* __restrict__ Vim, bf16_t* __restrict__ Bt) {
    int idx = blockIdx.x * 256 + threadIdx.x;   // 0 .. 512*512-1
    int j = idx >> 9;
    int c = idx & 511;
    union { unsigned int w; bf16_t h[2]; } pk;
    pk.h[0] = (bf16_t)Vre[j * P_DIM + c];
    pk.h[1] = (bf16_t)(-Vim[j * P_DIM + c]);
    ((unsigned int*)Bt)[idx] = pk.w;
}

// Phase 3: recompute local scan with carry init; write A row-major [t][1024]
// bf16, k-interleaved; one packed dword store per step (coalesced).
__global__ void __launch_bounds__(P_DIM) k_materialize(const float* __restrict__ u,
        const float* __restrict__ Lam, const float* __restrict__ lstep,
        const float2* __restrict__ carry, bf16_t* __restrict__ A) {
    int p = threadIdx.x;
    int c = blockIdx.x;
    float ar, ai, br, bi;
    channel_consts(Lam, lstep, p, ar, ai, br, bi);
    float2 x0 = carry[c * P_DIM + p];
    float xr = x0.x, xi = x0.y;
    const float* up = u + (size_t)c * CHUNK * P_DIM + p;
    unsigned int* Ap32 = (unsigned int*)(A + (size_t)c * CHUNK * KDIM);
    #pragma unroll 8
    for (int t = 0; t < CHUNK; ++t) {
        float uv = up[(size_t)t * P_DIM];
        float nr = ar * xr - ai * xi + br * uv;
        float ni = ar * xi + ai * xr + bi * uv;
        xr = nr; xi = ni;
        union { unsigned int w; bf16_t h[2]; } pk;
        pk.h[0] = (bf16_t)xr;
        pk.h[1] = (bf16_t)xi;
        Ap32[(size_t)t * (KDIM / 2) + p] = pk.w;
    }
}

// GEMM: out[m][n] = spike(sum_k A[m][k]*Bt[n][k]).
// m97 recipe: 128x128 tile, BK=64, 256 thr (4 waves, 2x2 of 64x64),
// global_load_lds width-16 staging. Global source order is XOR-swizzled so
// the lane-linear LDS layout gives conflict-free (2-way) ds_read_b128:
// LDS slot (row r, chunk sc) holds global chunk (r, sc ^ (r&7)).
__global__ void __launch_bounds__(256) k_gemm(const bf16_t* __restrict__ A,
        const bf16_t* __restrict__ Bt, float* __restrict__ out) {
    __shared__ __align__(16) bf16_t As[BM * BK];   // 16 KB
    __shared__ __align__(16) bf16_t Bs[BN * BK];   // 16 KB

    const int tid  = threadIdx.x;
    const int lane = tid & 63;
    const int w    = tid >> 6;
    const int m0   = blockIdx.x * BM;
    const int n0   = blockIdx.y * BN;
    const int wm   = (w >> 1) * 64;
    const int wn   = (w & 1) * 64;
    const int fr_m = lane & 15;
    const int fr_g = lane >> 4;

    floatx4 acc[4][4];
    #pragma unroll
    for (int i = 0; i < 4; ++i)
        #pragma unroll
        for (int j = 0; j < 4; ++j) {
            floatx4 z = {0.f, 0.f, 0.f, 0.f};
            acc[i][j] = z;
        }

    const bf16_t* Asrc = A  + (size_t)m0 * KDIM;
    const bf16_t* Bsrc = Bt + (size_t)n0 * KDIM;

    for (int kt = 0; kt < KDIM; kt += BK) {
        __syncthreads();
        // Stage: 1024 16B-chunks per operand; wave-uniform LDS base + lane*16.
        #pragma unroll
        for (int i = 0; i < 4; ++i) {
            const int cb = i * 256 + w * 64;        // uniform per wave
            const int c  = cb + lane;
            const int r  = c >> 3;                  // tile row (8 chunks/row)
            const int gc = (c & 7) ^ (r & 7);       // swizzled global chunk col
            const bf16_t* ga = Asrc + (size_t)r * KDIM + kt + gc * 8;
            const bf16_t* gb = Bsrc + (size_t)r * KDIM + kt + gc * 8;
            __builtin_amdgcn_global_load_lds(
                (const __attribute__((address_space(1))) unsigned int*)ga,
                (__attribute__((address_space(3))) unsigned int*)((char*)As + cb * 16),
                16, 0, 0);
            __builtin_amdgcn_global_load_lds(
                (const __attribute__((address_space(1))) unsigned int*)gb,
                (__attribute__((address_space(3))) unsigned int*)((char*)Bs + cb * 16),
                16, 0, 0);
        }
        __syncthreads();

        #pragma unroll
        for (int kk = 0; kk < BK; kk += 32) {
            const int kc = (kk >> 3) + fr_g;        // logical chunk col 0..7
            bf16x8 af[4], bfv[4];
            #pragma unroll
            for (int i = 0; i < 4; ++i) {
                int m = wm + i * 16 + fr_m;
                af[i] = *(const bf16x8*)((const char*)As + m * (BK * 2)
                                         + ((kc ^ (m & 7)) << 4));
            }
            #pragma unroll
            for (int j = 0; j < 4; ++j) {
                int n = wn + j * 16 + fr_m;
                bfv[j] = *(const bf16x8*)((const char*)Bs + n * (BK * 2)
                                          + ((kc ^ (n & 7)) << 4));
            }
            #pragma unroll
            for (int i = 0; i < 4; ++i)
                #pragma unroll
                for (int j = 0; j < 4; ++j)
                    acc[i][j] = __builtin_amdgcn_mfma_f32_16x16x32_bf16(
                        af[i], bfv[j], acc[i][j], 0, 0, 0);
        }
    }

    // Epilogue: C/D layout col=lane&15, row=(lane>>4)*4+reg (m89-verified).
    #pragma unroll
    for (int i = 0; i < 4; ++i)
        #pragma unroll
        for (int j = 0; j < 4; ++j)
            #pragma unroll
            for (int r = 0; r < 4; ++r) {
                int rr = wm + i * 16 + fr_g * 4 + r;
                int cl = wn + j * 16 + fr_m;
                out[(size_t)(m0 + rr) * NDIM + (n0 + cl)] =
                    (acc[i][j][r] > 1.0f) ? 1.0f : 0.0f;
            }
}

extern "C" void kernel_launch(void* const* d_in, const int* in_sizes, int n_in,
                              void* d_out, int out_size, void* d_ws, size_t ws_size,
                              hipStream_t stream) {
    (void)in_sizes; (void)n_in; (void)out_size; (void)ws_size;
    const float* u     = (const float*)d_in[0];
    const float* Lam   = (const float*)d_in[1];
    const float* lstep = (const float*)d_in[2];
    const float* Vre   = (const float*)d_in[3];
    const float* Vim   = (const float*)d_in[4];
    float* out = (float*)d_out;

    char* ws = (char*)d_ws;
    float2* endv  = (float2*)(ws);                        // 1 MB
    float2* carry = (float2*)(ws + (1 << 20));            // 1 MB
    bf16_t* Bt    = (bf16_t*)(ws + (2 << 20));            // 1 MB
    bf16_t* A     = (bf16_t*)(ws + (4 << 20));            // 32 MB

    hipLaunchKernelGGL(k_scan_ends, dim3(NCHUNK), dim3(P_DIM), 0, stream,
                       u, Lam, lstep, endv);
    hipLaunchKernelGGL(k_bt, dim3(NDIM * P_DIM / 256), dim3(256), 0, stream,
                       Vre, Vim, Bt);
    hipLaunchKernelGGL(k_carry, dim3(1), dim3(P_DIM), 0, stream,
                       Lam, lstep, endv, carry);
    hipLaunchKernelGGL(k_materialize, dim3(NCHUNK), dim3(P_DIM), 0, stream,
                       u, Lam, lstep, carry, A);
    hipLaunchKernelGGL(k_gemm, dim3(L_LEN / BM, NDIM / BN), dim3(256), 0, stream,
                       A, Bt, out);
}